// Round 2
// baseline (413.629 us; speedup 1.0000x reference)
//
#include <hip/hip_runtime.h>

// DrawRope, single dispatch: each block zeroes its own frame (coalesced int4,
// L2-hot), rasterizes the two Bresenham segments + endpoints, then grid-strides
// the tail region [M*FRAME_INTS, out_size) with int4 zero stores.
//
// Coverage note: previous verified kernel zeroed out_size*sizeof(int) bytes
// (observed as 1.536 GB = 1.5e6 KiB fills in rocprof -> out_size = 384e6 ints,
// 4x the M*FRAME area). We preserve that exact coverage but do ALL of it in
// one well-occupied dispatch instead of {fused frames} + {serialized tail fill}.

#define IMAGE_H 200
#define IMAGE_W 200
#define FRAME_INTS (IMAGE_H * IMAGE_W * 3)   // 120000 ints per frame (480 KB)
#define FRAME_INT4S (FRAME_INTS / 4)         // 30000 int4 stores per frame
#define NT 256                               // 4 waves/block -> all 800 blocks resident

__device__ __forceinline__ void draw_segment(int* img, int c0, int r0, int c1, int r1) {
    // Exact replica of the reference Bresenham (inclusive endpoints).
    int dx = abs(c1 - c0);
    int dy = -abs(r1 - r0);
    int sc = (c0 < c1) ? 1 : -1;
    int sr = (r0 < r1) ? 1 : -1;
    int err = dx + dy;
    int c = c0, r = r0;
    while (true) {
        int* p = img + (r * IMAGE_W + c) * 3;
        p[0] = 128; p[1] = 128; p[2] = 128;
        if (c == c1 && r == r1) break;
        int e2 = 2 * err;
        if (e2 >= dy) { err += dy; c += sc; }
        if (e2 <= dx) { err += dx; r += sr; }
    }
}

__global__ __launch_bounds__(NT)
void draw_rope_fused(const float* __restrict__ x,
                     const float* __restrict__ resolution,
                     const float* __restrict__ origin,
                     int* __restrict__ out,
                     long long tail_ints,   // ints to zero past the frame area
                     int M) {
    const int m = blockIdx.x;  // frame index in [0, M)
    int* img = out + (size_t)m * FRAME_INTS;
    const int4 z = make_int4(0, 0, 0, 0);

    // ---- Phase 1: zero this frame with coalesced 16B stores ----
    int4* p4 = (int4*)img;
    for (int i = threadIdx.x; i < FRAME_INT4S; i += NT) p4[i] = z;

    // Pixel coords, exactly as reference (fp32): row = floor(y/res0+org0),
    // col = floor(x/res1+org1). Uniform across the block.
    const float res0 = resolution[0], res1 = resolution[1];
    const float org0 = origin[0],    org1 = origin[1];
    const float* xp = x + (size_t)m * 6;
    int rows[3], cols[3];
#pragma unroll
    for (int i = 0; i < 3; ++i) {
        rows[i] = (int)floorf(xp[2 * i + 1] / res0 + org0);
        cols[i] = (int)floorf(xp[2 * i + 0] / res1 + org1);
    }

    __syncthreads();  // frame fully zeroed (vmcnt drained per wave) before line stores

    // ---- Phase 2: lanes 0,1 draw segments p0->p1, p1->p2 (all writes 128,
    // overlap between segments benign). Lines are L2-hot from phase 1.
    if (threadIdx.x < 2) {
        const int s = threadIdx.x;
        draw_segment(img, cols[s], rows[s], cols[s + 1], rows[s + 1]);
    }
    __syncthreads();  // line stores drained before endpoint overwrites

    // ---- Phase 3: endpoints in reference scatter order (red p0, red p1, green p2).
    if (threadIdx.x == 0) {
        int* p0 = img + (rows[0] * IMAGE_W + cols[0]) * 3;
        p0[0] = 255; p0[1] = 0; p0[2] = 0;
        int* p1 = img + (rows[1] * IMAGE_W + cols[1]) * 3;
        p1[0] = 255; p1[1] = 0; p1[2] = 0;
        int* p2 = img + (rows[2] * IMAGE_W + cols[2]) * 3;
        p2[0] = 0; p2[1] = 255; p2[2] = 0;
    }

    // ---- Phase 4: zero the tail region (disjoint from all frame/draw writes,
    // so no sync needed). Grid-stride across all blocks, coalesced int4.
    if (tail_ints > 0) {
        int* tail = out + (size_t)M * FRAME_INTS;
        int4* t4 = (int4*)tail;
        const long long n4 = tail_ints >> 2;
        const long long stride = (long long)gridDim.x * NT;
        for (long long i = (long long)blockIdx.x * NT + threadIdx.x; i < n4; i += stride)
            t4[i] = z;
        // 0-3 leftover ints
        const int rem = (int)(tail_ints & 3);
        if (blockIdx.x == 0 && threadIdx.x < rem)
            tail[(n4 << 2) + threadIdx.x] = 0;
    }
}

extern "C" void kernel_launch(void* const* d_in, const int* in_sizes, int n_in,
                              void* d_out, int out_size, void* d_ws, size_t ws_size,
                              hipStream_t stream) {
    const float* x          = (const float*)d_in[0];  // [B,T,6]
    const float* resolution = (const float*)d_in[1];  // [2]
    const float* origin     = (const float*)d_in[2];  // [2]
    int* out                = (int*)d_out;

    const int M = in_sizes[0] / 6;  // frames

    const long long frame_total = (long long)M * FRAME_INTS;
    const long long total_ints  = (long long)out_size;  // prior coverage: out_size ints
    const long long tail_ints   = total_ints > frame_total ? total_ints - frame_total : 0;

    draw_rope_fused<<<M, NT, 0, stream>>>(x, resolution, origin, out, tail_ints, M);
}

// Round 3
// 411.574 us; speedup vs baseline: 1.0050x; 1.0050x over previous
//
#include <hip/hip_runtime.h>

// DrawRope, single dispatch, CORRECT coverage: out_size is a BYTE count
// (384e6 B = 96e6 ints = [16,50,200,200,3] int32 exactly). Previous rounds
// inherited a 4x over-zero (out_size*sizeof(int) bytes = 1.536 GB) from the
// original kernel; the 1.152 GB "tail" beyond the M frames is outside the
// compared tensor and is now dropped (-195 us predicted).
//
// Structure (validated rounds 1-2): each block zeroes its own 480 KB frame
// with coalesced int4 stores (contiguous stream, fill-kernel-like), then
// rasterizes the two Bresenham segments + endpoints into L2-hot lines.

#define IMAGE_H 200
#define IMAGE_W 200
#define FRAME_INTS (IMAGE_H * IMAGE_W * 3)   // 120000 ints per frame (480 KB)
#define FRAME_INT4S (FRAME_INTS / 4)         // 30000 int4 stores per frame
#define NT 256                               // 4 waves/block; 800 blocks all resident

__device__ __forceinline__ void draw_segment(int* img, int c0, int r0, int c1, int r1) {
    // Exact replica of the reference Bresenham (inclusive endpoints).
    int dx = abs(c1 - c0);
    int dy = -abs(r1 - r0);
    int sc = (c0 < c1) ? 1 : -1;
    int sr = (r0 < r1) ? 1 : -1;
    int err = dx + dy;
    int c = c0, r = r0;
    while (true) {
        int* p = img + (r * IMAGE_W + c) * 3;
        p[0] = 128; p[1] = 128; p[2] = 128;
        if (c == c1 && r == r1) break;
        int e2 = 2 * err;
        if (e2 >= dy) { err += dy; c += sc; }
        if (e2 <= dx) { err += dx; r += sr; }
    }
}

__global__ __launch_bounds__(NT)
void draw_rope_fused(const float* __restrict__ x,
                     const float* __restrict__ resolution,
                     const float* __restrict__ origin,
                     int* __restrict__ out) {
    const int m = blockIdx.x;  // frame index in [0, M)
    int* img = out + (size_t)m * FRAME_INTS;

    // ---- Phase 1: zero this frame, coalesced 16B stores, contiguous 480 KB ----
    int4* p4 = (int4*)img;
    const int4 z = make_int4(0, 0, 0, 0);
    for (int i = threadIdx.x; i < FRAME_INT4S; i += NT) p4[i] = z;

    // Pixel coords, exactly as reference (fp32): row = floor(y/res0+org0),
    // col = floor(x/res1+org1). Uniform across the block.
    const float res0 = resolution[0], res1 = resolution[1];
    const float org0 = origin[0],    org1 = origin[1];
    const float* xp = x + (size_t)m * 6;
    int rows[3], cols[3];
#pragma unroll
    for (int i = 0; i < 3; ++i) {
        rows[i] = (int)floorf(xp[2 * i + 1] / res0 + org0);
        cols[i] = (int)floorf(xp[2 * i + 0] / res1 + org1);
    }

    __syncthreads();  // frame fully zeroed before line stores

    // ---- Phase 2: lanes 0,1 draw segments p0->p1, p1->p2 (all writes 128,
    // overlap between the segments benign). Lines are L2-hot from phase 1.
    if (threadIdx.x < 2) {
        const int s = threadIdx.x;
        draw_segment(img, cols[s], rows[s], cols[s + 1], rows[s + 1]);
    }
    __syncthreads();  // line stores drained before endpoint overwrites

    // ---- Phase 3: endpoints in reference scatter order (red p0, red p1, green p2).
    if (threadIdx.x == 0) {
        int* p0 = img + (rows[0] * IMAGE_W + cols[0]) * 3;
        p0[0] = 255; p0[1] = 0; p0[2] = 0;
        int* p1 = img + (rows[1] * IMAGE_W + cols[1]) * 3;
        p1[0] = 255; p1[1] = 0; p1[2] = 0;
        int* p2 = img + (rows[2] * IMAGE_W + cols[2]) * 3;
        p2[0] = 0; p2[1] = 255; p2[2] = 0;
    }
}

extern "C" void kernel_launch(void* const* d_in, const int* in_sizes, int n_in,
                              void* d_out, int out_size, void* d_ws, size_t ws_size,
                              hipStream_t stream) {
    const float* x          = (const float*)d_in[0];  // [B,T,6]
    const float* resolution = (const float*)d_in[1];  // [2]
    const float* origin     = (const float*)d_in[2];  // [2]
    int* out                = (int*)d_out;            // [B,T,200,200,3] int32

    const int M = in_sizes[0] / 6;  // B*T = 800 frames

    // One dispatch: zero + draw per frame. Covers exactly the compared tensor
    // (M * FRAME_INTS ints = 384 MB). No tail writes.
    draw_rope_fused<<<M, NT, 0, stream>>>(x, resolution, origin, out);
}